// Round 9
// baseline (65.913 us; speedup 1.0000x reference)
//
#include <hip/hip_runtime.h>

// Problem constants (fixed by init_kwargs)
//   key:    [B=2, N=8, T_K=8, K_H=14, K_W=14, C=64]  f32
//   scores: [B=2, N=8, 1568, 1568]                   f32
//   h_emb:  [27, 64], w_emb: [27, 64], t_emb: [15, 64]
//   out:    [B, N, 1568, 1568] f32
//
// rel_h[bn, qh, k] = dot(h_emb[kh-qh+13, :], key[bn, k, :])   k = tk*196+kh*14+kw
// rel_w[bn, qw, k] = dot(w_emb[kw-qw+13, :], key[bn, k, :])
// rel_t[bn, tq, k] = dot(t_emb[tk-tq+ 7, :], key[bn, k, :])
// out[bn, (tq,qh,qw), k] = scores + rel_h + rel_w + rel_t

typedef float f4 __attribute__((ext_vector_type(4)));

#define BN_TOTAL    16
#define KLEN        1568
#define KLEN4       392
#define QLEN        1568
#define KV_TOTAL    (BN_TOTAL * KLEN)            // 25088 key vectors
#define REL_H_ELEMS (BN_TOTAL * 14 * KLEN)       // 351232
#define REL_T_ELEMS (BN_TOTAL * 8 * KLEN)        // 200704

#define EROWS  69     // 27 h + 27 w + 15 t
#define EPITCH 68     // 64 + 4 pad floats; 272B row stride (16B aligned)

// ---------------- stage 1: rel tables (R7 version, ~4.5 us) ----------------
__global__ __launch_bounds__(256) void rel_fused(const float* __restrict__ key,
                                                 const float* __restrict__ hemb,
                                                 const float* __restrict__ wemb,
                                                 const float* __restrict__ temb,
                                                 float* __restrict__ relh,
                                                 float* __restrict__ relw,
                                                 float* __restrict__ relt)
{
    __shared__ float se[EROWS * EPITCH];
    for (int idx = threadIdx.x; idx < EROWS * 64; idx += 256) {
        int row = idx >> 6, c = idx & 63;
        float v;
        if (row < 27)      v = hemb[row * 64 + c];
        else if (row < 54) v = wemb[(row - 27) * 64 + c];
        else               v = temb[(row - 54) * 64 + c];
        se[row * EPITCH + c] = v;
    }
    __syncthreads();

    int tid  = threadIdx.x;
    int s    = tid & 7;                         // q-slot
    int kv   = blockIdx.x * 32 + (tid >> 3);    // grid exact: 784 blocks
    int bn   = kv / KLEN;
    int k    = kv - bn * KLEN;
    int tk   = k / 196;
    int khw  = k - tk * 196;
    int kh   = khw / 14;
    int kw   = khw - kh * 14;

    f4 kr[16];
    const f4* kp = (const f4*)key + (size_t)kv * 16;
#pragma unroll
    for (int c = 0; c < 16; ++c) kr[c] = kp[c];

#pragma unroll
    for (int j = 0; j < 5; ++j) {
        int qi = s + 8 * j;                     // 0..39, guard <36
        if (qi < 36) {
            int row = (qi < 14) ? (kh - qi + 13)
                    : (qi < 28) ? (kw - qi + 54)
                                : (tk - qi + 89);
            float* dst = (qi < 14) ? relh + (size_t)(bn * 14 + qi) * KLEN
                       : (qi < 28) ? relw + (size_t)(bn * 14 + qi - 14) * KLEN
                                   : relt + (size_t)(bn * 8 + qi - 28) * KLEN;
            const f4* e = (const f4*)(se + row * EPITCH);
            f4 acc4 = {0.f, 0.f, 0.f, 0.f};
#pragma unroll
            for (int c = 0; c < 16; ++c) acc4 += kr[c] * e[c];
            dst[k] = acc4.x + acc4.y + acc4.z + acc4.w;
        }
    }
}

// ---------------- stage 2: broadcast-add ----------------------------------
// Block = (bn, tq, qh-half, CH4=28 chunk). Tile = 98 q-rows x 28 f4.
// LDS rows 0..13 = rel_w[qw], 14..20 = rel_h[qh]+rel_t (folded) = 9.4 KB
// -> 8 blocks/CU co-resident, grid 3584 = 14/CU: steady-state 32 waves/CU.
// 2-deep pipeline, 2 f4 per thread-group, NT stores (R7 structure).
#define CH4    28                   // f4 per chunk (448 B, 7 cache lines)
#define NCH    14                   // 392 / 28
#define SROWS  21                   // 14 w + 7 ht
#define STAGE4 (SROWS * CH4)        // 588 f4 = 9408 B LDS
#define TILE4  (98 * CH4)           // 2744 f4 = 10*256 + 184

__global__ __launch_bounds__(256, 8) void add_staged(const f4* __restrict__ scores,
                                                     const f4* __restrict__ relh,
                                                     const f4* __restrict__ relw,
                                                     const f4* __restrict__ relt,
                                                     f4* __restrict__ out)
{
    __shared__ f4 se[STAGE4];

    int tid = threadIdx.x;
    int b   = blockIdx.x;
    int ch  = b % NCH;  b /= NCH;
    int half = b & 1;   b >>= 1;
    int tq  = b & 7;
    int bn  = b >> 3;
    int cbase = ch * CH4;

    // stage rel into LDS; fold t into the h rows
    {
        const f4* wrow = relw + (size_t)(bn * 14) * KLEN4 + cbase;
        const f4* hrow = relh + (size_t)(bn * 14 + half * 7) * KLEN4 + cbase;
        const f4* trow = relt + (size_t)(bn * 8 + tq) * KLEN4 + cbase;
        for (int e = tid; e < STAGE4; e += 256) {
            int r = e / CH4, c = e - r * CH4;
            f4 v;
            if (r < 14) v = wrow[(size_t)r * KLEN4 + c];
            else        v = hrow[(size_t)(r - 14) * KLEN4 + c] + trow[c];
            se[e] = v;
        }
    }

    int obase = (bn * QLEN + tq * 196 + half * 98) * KLEN4 + cbase;

#define EIDX(J, e, row, c, gi)                        \
    int e   = tid + (J) * 256;                        \
    int row = e / CH4;                                \
    int c   = e - row * CH4;                          \
    int gi  = obase + row * KLEN4 + c;

#define LOAD2(G, sv)                                  \
    {                                                 \
        _Pragma("unroll")                             \
        for (int jj = 0; jj < 2; ++jj) {              \
            EIDX(2 * (G) + jj, e, row, c, gi)         \
            sv[jj] = scores[gi];                      \
        }                                             \
    }

#define PROC2(G, sv)                                  \
    {                                                 \
        _Pragma("unroll")                             \
        for (int jj = 0; jj < 2; ++jj) {              \
            EIDX(2 * (G) + jj, e, row, c, gi)         \
            int qhl = row / 14, qw = row - qhl * 14;  \
            f4 v = sv[jj] + se[qw * CH4 + c]          \
                          + se[(14 + qhl) * CH4 + c]; \
            __builtin_nontemporal_store(v, out + gi); \
        }                                             \
    }

    f4 sA[2], sB[2];

    LOAD2(0, sA);
    LOAD2(1, sB);
    __syncthreads();            // stage + first loads complete

    PROC2(0, sA);  LOAD2(2, sA);
    PROC2(1, sB);  LOAD2(3, sB);
    PROC2(2, sA);  LOAD2(4, sA);
    PROC2(3, sB);
    PROC2(4, sA);

    // tail: 184 threads, one f4 each (element group 10)
    if (tid < TILE4 - 10 * 256) {
        EIDX(10, e, row, c, gi)
        int qhl = row / 14, qw = row - qhl * 14;
        f4 v = scores[gi] + se[qw * CH4 + c] + se[(14 + qhl) * CH4 + c];
        __builtin_nontemporal_store(v, out + gi);
    }
#undef EIDX
#undef LOAD2
#undef PROC2
}

extern "C" void kernel_launch(void* const* d_in, const int* in_sizes, int n_in,
                              void* d_out, int out_size, void* d_ws, size_t ws_size,
                              hipStream_t stream)
{
    const float* key    = (const float*)d_in[0];
    const float* scores = (const float*)d_in[1];
    const float* hemb   = (const float*)d_in[2];
    const float* wemb   = (const float*)d_in[3];
    const float* temb   = (const float*)d_in[4];
    float*       out    = (float*)d_out;

    size_t need = (size_t)(REL_H_ELEMS * 2 + REL_T_ELEMS) * sizeof(float); // ~3.45 MB
    if (ws_size < need) return;

    float* relh = (float*)d_ws;
    float* relw = relh + REL_H_ELEMS;
    float* relt = relw + REL_H_ELEMS;

    rel_fused<<<KV_TOTAL * 8 / 256, 256, 0, stream>>>(key, hemb, wemb, temb,
                                                      relh, relw, relt);

    // grid = bn(16) * tq(8) * half(2) * chunks(14) = 3584 blocks = 14/CU
    add_staged<<<BN_TOTAL * 8 * 2 * NCH, 256, 0, stream>>>((const f4*)scores,
                                                           (const f4*)relh,
                                                           (const f4*)relw,
                                                           (const f4*)relt,
                                                           (f4*)out);
}

// Round 10
// 59.153 us; speedup vs baseline: 1.1143x; 1.1143x over previous
//
#include <hip/hip_runtime.h>

// Problem constants (fixed by init_kwargs)
//   key:    [B=2, N=8, T_K=8, K_H=14, K_W=14, C=64]  f32
//   scores: [B=2, N=8, 1568, 1568]                   f32
//   h_emb:  [27, 64], w_emb: [27, 64], t_emb: [15, 64]
//   out:    [B, N, 1568, 1568] f32
//
// rel_h[bn, qh, k] = dot(h_emb[kh-qh+13, :], key[bn, k, :])   k = tk*196+kh*14+kw
// rel_w[bn, qw, k] = dot(w_emb[kw-qw+13, :], key[bn, k, :])
// rel_t[bn, tq, k] = dot(t_emb[tk-tq+ 7, :], key[bn, k, :])
// out[bn, (tq,qh,qw), k] = scores + rel_h + rel_w + rel_t

typedef float f4 __attribute__((ext_vector_type(4)));

#define BN_TOTAL    16
#define KLEN        1568
#define KLEN4       392
#define QLEN        1568
#define KV_TOTAL    (BN_TOTAL * KLEN)            // 25088 key vectors
#define REL_H_ELEMS (BN_TOTAL * 14 * KLEN)       // 351232
#define REL_T_ELEMS (BN_TOTAL * 8 * KLEN)        // 200704

#define EROWS  69     // 27 h + 27 w + 15 t
#define EPITCH 68     // 64 + 4 pad floats; 272B row stride (16B aligned)

// ---------------- stage 1: rel tables (R7 4-thread version) ----------------
__global__ __launch_bounds__(256) void rel_fused(const float* __restrict__ key,
                                                 const float* __restrict__ hemb,
                                                 const float* __restrict__ wemb,
                                                 const float* __restrict__ temb,
                                                 float* __restrict__ relh,
                                                 float* __restrict__ relw,
                                                 float* __restrict__ relt)
{
    __shared__ float se[EROWS * EPITCH];
    for (int idx = threadIdx.x; idx < EROWS * 64; idx += 256) {
        int row = idx >> 6, c = idx & 63;
        float v;
        if (row < 27)      v = hemb[row * 64 + c];
        else if (row < 54) v = wemb[(row - 27) * 64 + c];
        else               v = temb[(row - 54) * 64 + c];
        se[row * EPITCH + c] = v;
    }
    __syncthreads();

    int tid  = threadIdx.x;
    int s    = tid & 3;                         // q-slot
    int kv   = blockIdx.x * 64 + (tid >> 2);    // grid exact: 392 blocks
    int bn   = kv / KLEN;
    int k    = kv - bn * KLEN;
    int tk   = k / 196;
    int khw  = k - tk * 196;
    int kh   = khw / 14;
    int kw   = khw - kh * 14;

    f4 kr[16];
    const f4* kp = (const f4*)key + (size_t)kv * 16;
#pragma unroll
    for (int c = 0; c < 16; ++c) kr[c] = kp[c];

#pragma unroll
    for (int j = 0; j < 9; ++j) {
        int qi = s + 4 * j;                     // 0..35
        int row = (qi < 14) ? (kh - qi + 13)
                : (qi < 28) ? (kw - qi + 54)
                            : (tk - qi + 89);
        float* dst = (qi < 14) ? relh + (size_t)(bn * 14 + qi) * KLEN
                   : (qi < 28) ? relw + (size_t)(bn * 14 + qi - 14) * KLEN
                               : relt + (size_t)(bn * 8 + qi - 28) * KLEN;
        const f4* e = (const f4*)(se + row * EPITCH);
        f4 acc4 = {0.f, 0.f, 0.f, 0.f};
#pragma unroll
        for (int c = 0; c < 16; ++c) acc4 += kr[c] * e[c];
        dst[k] = acc4.x + acc4.y + acc4.z + acc4.w;
    }
}

// ---------------- stage 2: broadcast-add (R7 structure + XCD swizzle) ------
// Block = (bn, tq, qh-half, chunk). Tile = 98 q-rows x 56 f4 columns.
// LDS rows 0..13 = rel_w[qw], 14..20 = rel_h[qh] + rel_t (folded).
// XCD swizzle: 1792 blocks = 8 XCDs x 224; all 112 blocks of one bn map to
// one XCD so that bn's rel tables (~226 KB) stay L2-resident there.
#define CH4    56                   // f4 per chunk (896 B segments)
#define NCH    7                    // 392 / 56
#define SROWS  21                   // 14 w + 7 ht
#define STAGE4 (SROWS * CH4)        // 1176 f4 = 18816 B LDS
#define TILE4  (98 * CH4)           // 5488 f4 = 21*256 + 112

__global__ __launch_bounds__(256) void add_staged(const f4* __restrict__ scores,
                                                  const f4* __restrict__ relh,
                                                  const f4* __restrict__ relw,
                                                  const f4* __restrict__ relt,
                                                  f4* __restrict__ out)
{
    __shared__ f4 se[STAGE4];

    int tid  = threadIdx.x;
    // ---- XCD-aware decode: p%8 = XCD (round-robin dispatch heuristic) ----
    int p    = blockIdx.x;
    int xcd  = p & 7;
    int slot = p >> 3;                 // 0..223
    int hi   = (slot >= 112) ? 1 : 0;
    int bn   = xcd * 2 + hi;
    int inner = slot - hi * 112;       // 0..111 = (tq,half,ch)
    int ch   = inner % NCH;
    int tmp  = inner / NCH;            // 0..15
    int half = tmp & 1;
    int tq   = tmp >> 1;
    int cbase = ch * CH4;

    const f4* wrow = relw + (size_t)(bn * 14) * KLEN4 + cbase;
    const f4* hrow = relh + (size_t)(bn * 14 + half * 7) * KLEN4 + cbase;
    const f4* trow = relt + (size_t)(bn * 8 + tq) * KLEN4 + cbase;

    // stage rel into LDS; fold t into the h rows
    for (int e = tid; e < STAGE4; e += 256) {
        int r = e / CH4, c = e - r * CH4;
        f4 v;
        if (r < 14) v = wrow[(size_t)r * KLEN4 + c];
        else        v = hrow[(size_t)(r - 14) * KLEN4 + c] + trow[c];
        se[e] = v;
    }

    int obase = (bn * QLEN + tq * 196 + half * 98) * KLEN4 + cbase;

#define EIDX(J, e, row, c, gi)                        \
    int e   = tid + (J) * 256;                        \
    int row = e / CH4;                                \
    int c   = e - row * CH4;                          \
    int gi  = obase + row * KLEN4 + c;

#define LOAD3(G, sv)                                  \
    {                                                 \
        _Pragma("unroll")                             \
        for (int jj = 0; jj < 3; ++jj) {              \
            EIDX(3 * (G) + jj, e, row, c, gi)         \
            sv[jj] = scores[gi];                      \
        }                                             \
    }

#define PROC3(G, sv)                                  \
    {                                                 \
        _Pragma("unroll")                             \
        for (int jj = 0; jj < 3; ++jj) {              \
            EIDX(3 * (G) + jj, e, row, c, gi)         \
            int qhl = row / 14, qw = row - qhl * 14;  \
            f4 v = sv[jj] + se[qw * CH4 + c]          \
                          + se[(14 + qhl) * CH4 + c]; \
            __builtin_nontemporal_store(v, out + gi); \
        }                                             \
    }

    f4 sA[3], sB[3];

    LOAD3(0, sA);
    LOAD3(1, sB);
    __syncthreads();            // stage complete (also drains sA/sB loads)

    PROC3(0, sA);  LOAD3(2, sA);
    PROC3(1, sB);  LOAD3(3, sB);
    PROC3(2, sA);  LOAD3(4, sA);
    PROC3(3, sB);  LOAD3(5, sB);
    PROC3(4, sA);  LOAD3(6, sA);
    PROC3(5, sB);
    PROC3(6, sA);

    // tail: 112 threads, one f4 each (group index 21)
    if (tid < TILE4 - 21 * 256) {
        EIDX(21, e, row, c, gi)
        int qhl = row / 14, qw = row - qhl * 14;
        f4 v = scores[gi] + se[qw * CH4 + c] + se[(14 + qhl) * CH4 + c];
        __builtin_nontemporal_store(v, out + gi);
    }
#undef EIDX
#undef LOAD3
#undef PROC3
}

extern "C" void kernel_launch(void* const* d_in, const int* in_sizes, int n_in,
                              void* d_out, int out_size, void* d_ws, size_t ws_size,
                              hipStream_t stream)
{
    const float* key    = (const float*)d_in[0];
    const float* scores = (const float*)d_in[1];
    const float* hemb   = (const float*)d_in[2];
    const float* wemb   = (const float*)d_in[3];
    const float* temb   = (const float*)d_in[4];
    float*       out    = (float*)d_out;

    size_t need = (size_t)(REL_H_ELEMS * 2 + REL_T_ELEMS) * sizeof(float); // ~3.45 MB
    if (ws_size < need) return;

    float* relh = (float*)d_ws;
    float* relw = relh + REL_H_ELEMS;
    float* relt = relw + REL_H_ELEMS;

    rel_fused<<<KV_TOTAL * 4 / 256, 256, 0, stream>>>(key, hemb, wemb, temb,
                                                      relh, relw, relt);

    // grid = 1792 blocks = 8 XCDs * 224 (bn-per-XCD swizzle decoded in-kernel)
    add_staged<<<BN_TOTAL * 8 * 2 * NCH, 256, 0, stream>>>((const f4*)scores,
                                                           (const f4*)relh,
                                                           (const f4*)relw,
                                                           (const f4*)relt,
                                                           (f4*)out);
}